// Round 1
// baseline (260.318 us; speedup 1.0000x reference)
//
#include <hip/hip_runtime.h>
#include <hip/hip_bf16.h>
#include <stdint.h>

#define HN 16      // heads
#define TT 2048    // seq len (T == S)
#define BBATCH 2
#define EE 1024
#define HD 64
#define MM 4096    // TT*BBATCH

// Q projection pre-scaled by 0.125*log2(e): exp2(q'.k) == exp(0.125*q.k).
#define SCALEQ 0.18033688011112042f

typedef __attribute__((ext_vector_type(8))) __bf16 bfrag;
typedef __attribute__((ext_vector_type(4))) float f32x4;
typedef __attribute__((ext_vector_type(4))) short s16x4;

__device__ __forceinline__ void gll16(const void* g, void* lds) {
  __builtin_amdgcn_global_load_lds(
      (const __attribute__((address_space(1))) void*)g,
      (__attribute__((address_space(3))) void*)lds, 16, 0, 0);
}

__device__ __forceinline__ f32x4 mfma_bf16(bfrag a, bfrag b, f32x4 c) {
  return __builtin_amdgcn_mfma_f32_16x16x32_bf16(a, b, c, 0, 0, 0);
}

// ---- XOR-swizzled 64-elem-row LDS tiles (16B chunk c of row r at c^(r&7)) --
__device__ __forceinline__ const bfrag* fragp(const __bf16* base, int row, int e) {
  return (const bfrag*)(base + row * 64 + ((((e >> 3) ^ row) & 7) << 3));
}
__device__ __forceinline__ void stage8(const __bf16* grow0, int gstride,
                                       __bf16* tile, int r0, int lane) {
  const int rr = lane >> 3;
  const int cl = (lane & 7) ^ rr;
  gll16(grow0 + (size_t)(r0 + rr) * gstride + cl * 8, tile + r0 * 64);
}

// ---------------- fp32 -> bf16 conversion (7 tensors in one launch) -------
struct CvtArgs {
  const float* src[7];
  __bf16* dst[7];
  int n4[7];
};

__global__ __launch_bounds__(256) void cvt_all(CvtArgs a) {
  const int z = blockIdx.z;
  const int i = blockIdx.x * 256 + threadIdx.x;
  if (i < a.n4[z]) {
    float4 v = ((const float4*)a.src[z])[i];
    struct alignas(8) B4 { __bf16 a0, a1, a2, a3; };
    B4 o = {(__bf16)v.x, (__bf16)v.y, (__bf16)v.z, (__bf16)v.w};
    ((B4*)a.dst[z])[i] = o;
  }
}

// ---------------- GEMM core v2 (kept for the output GEMM): BK=64 ----------
template <int MT>
__device__ __forceinline__ void gemm2(const __bf16* __restrict__ X,
                                      const __bf16* __restrict__ W,
                                      const float* __restrict__ bias,
                                      void* __restrict__ out, int mode,
                                      float scale, int m0, int n0,
                                      __bf16* As0, __bf16* As1,
                                      __bf16* Bs0, __bf16* Bs1) {
  const int tid = threadIdx.x, lane = tid & 63, w = tid >> 6;
  const int wm = w >> 1, wn = w & 1;
  const int quad = lane >> 4, l16 = lane & 15;
  constexpr int FM = MT / 32;   // m-frags per wave

  auto stageAB = [&](int buf, int k0) {
    __bf16* A = buf ? As1 : As0;
    __bf16* B = buf ? Bs1 : Bs0;
    #pragma unroll
    for (int c = 0; c < FM; ++c)
      stage8(X + (size_t)m0 * EE + k0, EE, A, w * (MT / 4) + c * 8, lane);
    #pragma unroll
    for (int c = 0; c < 4; ++c)
      stage8(W + (size_t)n0 * EE + k0, EE, B, w * 32 + c * 8, lane);
  };

  stageAB(0, 0);

  f32x4 acc[FM][4] = {};

  for (int it = 0; it < EE / 64; ++it) {
    const int cur = it & 1;
    __syncthreads();                 // buf[cur] staged; prior reads done
    if (it + 1 < EE / 64) stageAB(1 - cur, (it + 1) * 64);

    const __bf16* A = cur ? As1 : As0;
    const __bf16* B = cur ? Bs1 : Bs0;
    #pragma unroll
    for (int ks = 0; ks < 2; ++ks) {
      bfrag a[FM], b[4];
      #pragma unroll
      for (int f = 0; f < FM; ++f)
        a[f] = *fragp(A, wm * (MT / 2) + f * 16 + l16, ks * 32 + quad * 8);
      #pragma unroll
      for (int f = 0; f < 4; ++f)
        b[f] = *fragp(B, wn * 64 + f * 16 + l16, ks * 32 + quad * 8);
      #pragma unroll
      for (int fm = 0; fm < FM; ++fm)
        #pragma unroll
        for (int fn = 0; fn < 4; ++fn)
          acc[fm][fn] = mfma_bf16(a[fm], b[fn], acc[fm][fn]);
    }
  }

  float bv[4];
  #pragma unroll
  for (int fn = 0; fn < 4; ++fn) bv[fn] = bias[n0 + wn * 64 + fn * 16 + l16];

  #pragma unroll
  for (int fm = 0; fm < FM; ++fm) {
    #pragma unroll
    for (int r = 0; r < 4; ++r) {
      const int gm = m0 + wm * (MT / 2) + fm * 16 + quad * 4 + r;
      #pragma unroll
      for (int fn = 0; fn < 4; ++fn) {
        const int gn = n0 + wn * 64 + fn * 16 + l16;
        const float v = (acc[fm][fn][r] + bv[fn]) * scale;
        if (mode == 0) {
          const int t = gm >> 1, bb = gm & 1, h = gn >> 6, d = gn & 63;
          ((__bf16*)out)[(((size_t)(bb * HN + h)) * TT + t) * HD + d] = (__bf16)v;
        } else if (mode == 2) {
          const int s = gm >> 1, bb = gm & 1, h = gn >> 6, d = gn & 63;
          ((__bf16*)out)[(((size_t)(bb * HN + h)) * HD + d) * TT + s] = (__bf16)v;
        } else {
          ((float*)out)[(size_t)gm * EE + gn] = v;
        }
      }
    }
  }
}

// ---------------- QKV GEMM: 256x256 tile, BK=64, 8-phase counted-vmcnt ----
// 512 thr = 8 waves (2M x 4N); per-wave C = 128x64 (8x4 16x16 frags).
// LDS: 2 bufs x (A 256x64 + B 256x64) bf16 = 128 KB. Even K-tiles buf0,
// odd buf1. Per 8-phase iter (2 K-tiles): stage slots ph1 = kt1-B,
// ph4 = next-even-A, ph5 = next-even-B, ph8 = next-odd-A; quadrant order
// (0,0)(0,1)(1,1)(1,0) makes ph4/ph8 ds_read-free so those buffers are
// overwrite-safe after the ph3/ph7 barriers. vmcnt(4) gates ONLY at
// ph4/ph8 -> stage-to-consume distance is 4 phases; loads never drain to
// 0 in the main loop (T3+T4). T2 swizzle via stage8/fragp, T5 setprio.
__global__ __launch_bounds__(512, 2) void gemm_qkv8(
    const __bf16* __restrict__ xq, const __bf16* __restrict__ xk,
    const __bf16* __restrict__ xv, const __bf16* __restrict__ wq,
    const __bf16* __restrict__ wk, const __bf16* __restrict__ wv,
    const float* __restrict__ bq, const float* __restrict__ bk,
    const float* __restrict__ bv, __bf16* __restrict__ qo,
    __bf16* __restrict__ ko, __bf16* __restrict__ vo) {
  __shared__ __bf16 As[2][256 * 64];   // 64KB
  __shared__ __bf16 Bs[2][256 * 64];   // 64KB
  const int tid = threadIdx.x, lane = tid & 63, w = tid >> 6;
  const int wm = w >> 2, wn = w & 3;
  const int quad = lane >> 4, l16 = lane & 15;

  // bx = m + 16*n + 64*z: the 4 n-blocks sharing an A-tile have equal bx%8
  // -> same XCD (A stays in that XCD's L2).
  const int bx = blockIdx.x;
  const int m = bx & 15, n = (bx >> 4) & 3, z = bx >> 6;
  const __bf16 *X, *W;
  const float* bias;
  __bf16* out;
  int mode;
  float scale;
  if (z == 0)      { X = xq; W = wq; bias = bq; out = qo; mode = 0; scale = SCALEQ; }
  else if (z == 1) { X = xk; W = wk; bias = bk; out = ko; mode = 0; scale = 1.0f; }
  else             { X = xv; W = wv; bias = bv; out = vo; mode = 2; scale = 1.0f; }
  const int m0 = m * 256, n0 = n * 256;
  const __bf16* Ag = X + (size_t)m0 * EE;
  const __bf16* Bg = W + (size_t)n0 * EE;
  __bf16* As0 = As[0]; __bf16* As1 = As[1];
  __bf16* Bs0 = Bs[0]; __bf16* Bs1 = Bs[1];

  // one 128-row half-tile = 2 gll16/thread (8 waves x 16 rows)
  auto stageHalf = [&](const __bf16* g, __bf16* tile, int r0) {
    #pragma unroll
    for (int c = 0; c < 2; ++c)
      stage8(g, EE, tile, r0 + w * 16 + c * 8, lane);
  };

  // prologue: T0 full (8 loads), T1-A (4 loads); retire T0, keep T1-A flying
  stageHalf(Ag, As0, 0);      stageHalf(Ag, As0, 128);
  stageHalf(Bg, Bs0, 0);      stageHalf(Bg, Bs0, 128);
  stageHalf(Ag + 64, As1, 0); stageHalf(Ag + 64, As1, 128);
  asm volatile("s_waitcnt vmcnt(4)" ::: "memory");
  __builtin_amdgcn_s_barrier();

  f32x4 acc[8][4] = {};

  // 4 phases over one K-tile (64 K) held in (Ac,Bc).
  // gate: 0 -> vmcnt(4) at phase D, 1 -> vmcnt(0), 2 -> none.
  auto quad4 = [&](const __bf16* Ac, const __bf16* Bc,
                   const __bf16* g1, __bf16* l1, bool do1,
                   const __bf16* g4, __bf16* l4, bool do4, int gate) {
    bfrag a[4][2], b0[2][2], b1[2][2];
    // ---- phase A: read A-low(8) + B-low(4); stage slot 1; MFMA (0,0)
    #pragma unroll
    for (int f = 0; f < 4; ++f)
      #pragma unroll
      for (int ks = 0; ks < 2; ++ks)
        a[f][ks] = *fragp(Ac, wm * 128 + f * 16 + l16, ks * 32 + quad * 8);
    #pragma unroll
    for (int f = 0; f < 2; ++f)
      #pragma unroll
      for (int ks = 0; ks < 2; ++ks)
        b0[f][ks] = *fragp(Bc, wn * 64 + f * 16 + l16, ks * 32 + quad * 8);
    if (do1) { stageHalf(g1, l1, 0); stageHalf(g1, l1, 128); }
    __builtin_amdgcn_s_barrier();
    asm volatile("s_waitcnt lgkmcnt(0)" ::: "memory");
    __builtin_amdgcn_sched_barrier(0);
    __builtin_amdgcn_s_setprio(1);
    #pragma unroll
    for (int ks = 0; ks < 2; ++ks)
      #pragma unroll
      for (int f = 0; f < 4; ++f)
        #pragma unroll
        for (int fn = 0; fn < 2; ++fn)
          acc[f][fn] = mfma_bf16(a[f][ks], b0[fn][ks], acc[f][fn]);
    __builtin_amdgcn_s_setprio(0);
    __builtin_amdgcn_s_barrier();
    // ---- phase B: read B-high(4); MFMA (0,1)
    #pragma unroll
    for (int f = 0; f < 2; ++f)
      #pragma unroll
      for (int ks = 0; ks < 2; ++ks)
        b1[f][ks] = *fragp(Bc, wn * 64 + (2 + f) * 16 + l16, ks * 32 + quad * 8);
    __builtin_amdgcn_s_barrier();
    asm volatile("s_waitcnt lgkmcnt(0)" ::: "memory");
    __builtin_amdgcn_sched_barrier(0);
    __builtin_amdgcn_s_setprio(1);
    #pragma unroll
    for (int ks = 0; ks < 2; ++ks)
      #pragma unroll
      for (int f = 0; f < 4; ++f)
        #pragma unroll
        for (int fn = 0; fn < 2; ++fn)
          acc[f][2 + fn] = mfma_bf16(a[f][ks], b1[fn][ks], acc[f][2 + fn]);
    __builtin_amdgcn_s_setprio(0);
    __builtin_amdgcn_s_barrier();
    // ---- phase C: read A-high(8); MFMA (1,1)
    #pragma unroll
    for (int f = 0; f < 4; ++f)
      #pragma unroll
      for (int ks = 0; ks < 2; ++ks)
        a[f][ks] = *fragp(Ac, wm * 128 + (4 + f) * 16 + l16, ks * 32 + quad * 8);
    __builtin_amdgcn_s_barrier();
    asm volatile("s_waitcnt lgkmcnt(0)" ::: "memory");
    __builtin_amdgcn_sched_barrier(0);
    __builtin_amdgcn_s_setprio(1);
    #pragma unroll
    for (int ks = 0; ks < 2; ++ks)
      #pragma unroll
      for (int f = 0; f < 4; ++f)
        #pragma unroll
        for (int fn = 0; fn < 2; ++fn)
          acc[4 + f][2 + fn] = mfma_bf16(a[f][ks], b1[fn][ks], acc[4 + f][2 + fn]);
    __builtin_amdgcn_s_setprio(0);
    __builtin_amdgcn_s_barrier();
    // ---- phase D: no ds_read; stage slot 4 (this buffer is read-free now);
    //      vmcnt gate retires the two stage-groups the NEXT 4 phases read.
    if (do4) { stageHalf(g4, l4, 0); stageHalf(g4, l4, 128); }
    if (gate == 0)      asm volatile("s_waitcnt vmcnt(4)" ::: "memory");
    else if (gate == 1) asm volatile("s_waitcnt vmcnt(0)" ::: "memory");
    __builtin_amdgcn_s_barrier();
    __builtin_amdgcn_s_setprio(1);
    #pragma unroll
    for (int ks = 0; ks < 2; ++ks)
      #pragma unroll
      for (int f = 0; f < 4; ++f)
        #pragma unroll
        for (int fn = 0; fn < 2; ++fn)
          acc[4 + f][fn] = mfma_bf16(a[f][ks], b0[fn][ks], acc[4 + f][fn]);
    __builtin_amdgcn_s_setprio(0);
    __builtin_amdgcn_s_barrier();
  };

  for (int i = 0; i < 8; ++i) {
    const int k0 = i * 128;
    const bool nl = (i < 7);
    // K-tile 2i (buf0): ph1 stages T(2i+1)-B, ph4 stages T(2i+2)-A.
    quad4(As0, Bs0, Bg + k0 + 64, Bs1, true,
          Ag + k0 + 128, As0, nl, nl ? 0 : 1);
    // K-tile 2i+1 (buf1): ph5 stages T(2i+2)-B, ph8 stages T(2i+3)-A.
    quad4(As1, Bs1, Bg + k0 + 128, Bs0, nl,
          Ag + k0 + 192, As1, nl, nl ? 0 : 2);
  }

  float bvv[4];
  #pragma unroll
  for (int fn = 0; fn < 4; ++fn) bvv[fn] = bias[n0 + wn * 64 + fn * 16 + l16];

  #pragma unroll
  for (int fm = 0; fm < 8; ++fm) {
    #pragma unroll
    for (int r = 0; r < 4; ++r) {
      const int gm = m0 + wm * 128 + fm * 16 + quad * 4 + r;
      #pragma unroll
      for (int fn = 0; fn < 4; ++fn) {
        const int gn = n0 + wn * 64 + fn * 16 + l16;
        const float v = (acc[fm][fn][r] + bvv[fn]) * scale;
        if (mode == 0) {
          const int t = gm >> 1, bb = gm & 1, h = gn >> 6, d = gn & 63;
          out[(((size_t)(bb * HN + h)) * TT + t) * HD + d] = (__bf16)v;
        } else {
          const int s = gm >> 1, bb = gm & 1, h = gn >> 6, d = gn & 63;
          out[(((size_t)(bb * HN + h)) * HD + d) * TT + s] = (__bf16)v;
        }
      }
    }
  }
}

// ---------------- flash attention fwd: O (normalized) + linv -------------
__global__ __launch_bounds__(256, 2) void attn_fwd(const __bf16* __restrict__ qb,
                                                   const __bf16* __restrict__ kb,
                                                   const __bf16* __restrict__ vtb,
                                                   __bf16* __restrict__ ob,
                                                   float* __restrict__ linv_ws) {
  union Sh {
    __bf16 kv[2][2][2][64 * 64];  // [pair][K=0/V=1][buf] 64KB
    float om[2][64 * 64];         // epilogue O-merge scratch (32KB, aliased)
  };
  __shared__ Sh sm;
  __shared__ float Lsum[2][128];
  __shared__ float LinvS[128];

  const int tid = threadIdx.x, lane = tid & 63, w = tid >> 6;
  const int p = w >> 1, tw = w & 1;
  const int quad = lane >> 4, l16 = lane & 15;

  const int bx = blockIdx.x;
  const int xcd = bx & 7, slot = bx >> 3;
  const int bhi = xcd * 4 + (slot >> 4);
  const int t0 = (slot & 15) * 128;
  const int b = bhi >> 4, h = bhi & 15;
  const size_t bh = (size_t)(b * HN + h);

  const __bf16* qbase = qb + (bh * TT + t0) * HD;
  const __bf16* kbase = kb + bh * TT * HD;
  const __bf16* vbase = vtb + bh * HD * TT;
  const int sBase = p * 1024;

  #pragma unroll
  for (int c = 0; c < 4; ++c) {
    stage8(kbase + (size_t)sBase * HD, HD, sm.kv[p][0][0], tw * 32 + c * 8, lane);
    stage8(vbase + sBase, TT, sm.kv[p][1][0], tw * 32 + c * 8, lane);
  }

  bfrag qf[4][2];
  #pragma unroll
  for (int fn = 0; fn < 4; ++fn)
    #pragma unroll
    for (int ks = 0; ks < 2; ++ks)
      qf[fn][ks] = *(const bfrag*)(qbase +
          (size_t)(tw * 64 + fn * 16 + l16) * HD + ks * 32 + quad * 8);

  bfrag ones;
  {
    union { short s[8]; bfrag v; } u;
    #pragma unroll
    for (int i = 0; i < 8; ++i) u.s[i] = 0x3F80;   // bf16 1.0
    ones = u.v;
  }

  f32x4 oacc[4][4] = {};   // [fm_d][fn_t] of O^T
  f32x4 lacc[4] = {};      // row sums via ones-MFMA (all r identical)

  for (int it = 0; it < 16; ++it) {
    const int cur = it & 1;
    __syncthreads();
    if (it + 1 < 16) {
      const int s1 = sBase + (it + 1) * 64;
      #pragma unroll
      for (int c = 0; c < 4; ++c) {
        stage8(kbase + (size_t)s1 * HD, HD, sm.kv[p][0][1 - cur], tw * 32 + c * 8, lane);
        stage8(vbase + s1, TT, sm.kv[p][1][1 - cur], tw * 32 + c * 8, lane);
      }
    }

    // ---- S^T[s][t] = K.Q (scale+log2e folded into Q)
    f32x4 sacc[4][4] = {};
    #pragma unroll
    for (int ks = 0; ks < 2; ++ks) {
      bfrag kf[4];
      #pragma unroll
      for (int fm = 0; fm < 4; ++fm)
        kf[fm] = *fragp(sm.kv[p][0][cur], fm * 16 + l16, ks * 32 + quad * 8);
      #pragma unroll
      for (int fm = 0; fm < 4; ++fm)
        #pragma unroll
        for (int fn = 0; fn < 4; ++fn)
          sacc[fm][fn] = mfma_bf16(kf[fm], qf[fn][ks], sacc[fm][fn]);
    }

    // ---- exp2 in registers; pack 16-s frag pairs into x32 B-operands
    union PB { __bf16 hh[8]; bfrag v; } pb[2][4];
    #pragma unroll
    for (int fm = 0; fm < 4; ++fm)
      #pragma unroll
      for (int fn = 0; fn < 4; ++fn) {
        const float p0 = __builtin_amdgcn_exp2f(sacc[fm][fn][0]);
        const float p1 = __builtin_amdgcn_exp2f(sacc[fm][fn][1]);
        const float p2 = __builtin_amdgcn_exp2f(sacc[fm][fn][2]);
        const float p3 = __builtin_amdgcn_exp2f(sacc[fm][fn][3]);
        const int hb = (fm & 1) * 4;
        pb[fm >> 1][fn].hh[hb + 0] = (__bf16)p0;
        pb[fm >> 1][fn].hh[hb + 1] = (__bf16)p1;
        pb[fm >> 1][fn].hh[hb + 2] = (__bf16)p2;
        pb[fm >> 1][fn].hh[hb + 3] = (__bf16)p3;
      }

    // ---- O^T[d][t] += V^T.P^T ; row sums l[t] += 1.P^T on the MFMA pipe
    #pragma unroll
    for (int ks = 0; ks < 2; ++ks) {
      bfrag vf[4];
      #pragma unroll
      for (int fm = 0; fm < 4; ++fm) {
        const __bf16* base = sm.kv[p][1][cur] + (fm * 16 + l16) * 64;
        const int sw = l16 & 7, qh = quad >> 1, qo = (quad & 1) * 4;
        union VF { s16x4 q[2]; bfrag v; } u;
        u.q[0] = *(const s16x4*)(base + (((ks * 4 + qh) ^ sw) << 3) + qo);
        u.q[1] = *(const s16x4*)(base + (((ks * 4 + 2 + qh) ^ sw) << 3) + qo);
        vf[fm] = u.v;
      }
      #pragma unroll
      for (int fn = 0; fn < 4; ++fn)
        lacc[fn] = mfma_bf16(ones, pb[ks][fn].v, lacc[fn]);
      #pragma unroll
      for (int fm = 0; fm < 4; ++fm)
        #pragma unroll
        for (int fn = 0; fn < 4; ++fn)
          oacc[fm][fn] = mfma_bf16(vf[fm], pb[ks][fn].v, oacc[fm][fn]);
    }
  }

  // ---- lacc[fn][r] holds l for t = fn*16+l16 (identical across r, quads)
  if (quad == 0)
    #pragma unroll
    for (int fn = 0; fn < 4; ++fn)
      Lsum[p][tw * 64 + fn * 16 + l16] = lacc[fn][0];

  __syncthreads();   // Lsum visible; all K/V reads done -> om may alias

  if (p == 1) {
    #pragma unroll
    for (int fm = 0; fm < 4; ++fm)
      #pragma unroll
      for (int fn = 0; fn < 4; ++fn)
        #pragma unroll
        for (int r = 0; r < 4; ++r)
          sm.om[tw][(fm * 16 + quad * 4 + r) * 64 + fn * 16 + l16] = oacc[fm][fn][r];
  }
  if (tid < 128) {
    const float linv = 1.0f / (Lsum[0][tid] + Lsum[1][tid]);
    LinvS[tid] = linv;
    linv_ws[bh * TT + t0 + tid] = linv;
  }
  __syncthreads();

  if (p == 0) {
    float li[4];
    #pragma unroll
    for (int fn = 0; fn < 4; ++fn) li[fn] = LinvS[tw * 64 + fn * 16 + l16];
    #pragma unroll
    for (int fm = 0; fm < 4; ++fm)
      #pragma unroll
      for (int fn = 0; fn < 4; ++fn) {
        const int t = t0 + tw * 64 + fn * 16 + l16;
        struct alignas(8) B4 { __bf16 a0, a1, a2, a3; };
        B4 o;
        __bf16* op = &o.a0;
        #pragma unroll
        for (int r = 0; r < 4; ++r) {
          const float v = (oacc[fm][fn][r] +
              sm.om[tw][(fm * 16 + quad * 4 + r) * 64 + fn * 16 + l16]) * li[fn];
          op[r] = (__bf16)v;
        }
        *(B4*)(ob + ((size_t)t * BBATCH + b) * EE + h * HD + fm * 16 + quad * 4) = o;
      }
  }
}

// ---------------- avg_w body: mean over heads of softmax probs ----------
__device__ __forceinline__ void avg_body(const __bf16* __restrict__ qb,
                                         const __bf16* __restrict__ kb,
                                         const float* __restrict__ linv_ws,
                                         float* __restrict__ avg_out, int bx,
                                         __bf16* Qs0, __bf16* Qs1,
                                         __bf16* Ks0, __bf16* Ks1) {
  const int tid = threadIdx.x, lane = tid & 63, w = tid >> 6;
  const int wm = w >> 1, wn = w & 1;
  const int quad = lane >> 4, l16 = lane & 15;

  const int xcd = bx & 7, slot = bx >> 3;
  const int bti = xcd * 4 + (slot >> 4);
  const int s0 = (slot & 15) * 128;
  const int b = bti >> 4, t0 = (bti & 15) * 128;

  const __bf16* qt = qb + (((size_t)b * HN) * TT + t0) * HD;
  const __bf16* kt = kb + (((size_t)b * HN) * TT + s0) * HD;
  const float* lrow0 = linv_ws + ((size_t)b * HN) * TT + t0 + wm * 64;

  #pragma unroll
  for (int c = 0; c < 4; ++c) {
    stage8(qt, HD, Qs0, w * 32 + c * 8, lane);
    stage8(kt, HD, Ks0, w * 32 + c * 8, lane);
  }

  f32x4 aacc[4][4] = {};

  for (int h = 0; h < HN; ++h) {
    const int cur = h & 1;
    __syncthreads();
    if (h + 1 < HN) {
      const __bf16* qn = qt + (size_t)(h + 1) * TT * HD;
      const __bf16* kn = kt + (size_t)(h + 1) * TT * HD;
      __bf16* Qn = cur ? Qs0 : Qs1;
      __bf16* Kn = cur ? Ks0 : Ks1;
      #pragma unroll
      for (int c = 0; c < 4; ++c) {
        stage8(qn, HD, Qn, w * 32 + c * 8, lane);
        stage8(kn, HD, Kn, w * 32 + c * 8, lane);
      }
    }

    const __bf16* Qc = cur ? Qs1 : Qs0;
    const __bf16* Kc = cur ? Ks1 : Ks0;
    f32x4 sacc[4][4] = {};
    #pragma unroll
    for (int ks = 0; ks < 2; ++ks) {
      bfrag qf4[4], kf4[4];
      #pragma unroll
      for (int f = 0; f < 4; ++f)
        qf4[f] = *fragp(Qc, wm * 64 + f * 16 + l16, ks * 32 + quad * 8);
      #pragma unroll
      for (int f = 0; f < 4; ++f)
        kf4[f] = *fragp(Kc, wn * 64 + f * 16 + l16, ks * 32 + quad * 8);
      #pragma unroll
      for (int fm = 0; fm < 4; ++fm)
        #pragma unroll
        for (int fn = 0; fn < 4; ++fn)
          sacc[fm][fn] = mfma_bf16(qf4[fm], kf4[fn], sacc[fm][fn]);
    }

    const float* lr = lrow0 + (size_t)h * TT;
    f32x4 lvv[4];
    #pragma unroll
    for (int fm = 0; fm < 4; ++fm)
      lvv[fm] = *(const f32x4*)(lr + fm * 16 + quad * 4);

    #pragma unroll
    for (int fm = 0; fm < 4; ++fm)
      #pragma unroll
      for (int fn = 0; fn < 4; ++fn)
        #pragma unroll
        for (int r = 0; r < 4; ++r)
          aacc[fm][fn][r] += __builtin_amdgcn_exp2f(sacc[fm][fn][r]) * lvv[fm][r];
  }

  const float invh = 1.0f / (float)HN;
  #pragma unroll
  for (int fm = 0; fm < 4; ++fm)
    #pragma unroll
    for (int r = 0; r < 4; ++r) {
      const int t = t0 + wm * 64 + fm * 16 + quad * 4 + r;
      #pragma unroll
      for (int fn = 0; fn < 4; ++fn) {
        const int s = s0 + wn * 64 + fn * 16 + l16;
        avg_out[((size_t)b * TT + t) * TT + s] = aacc[fm][fn][r] * invh;
      }
    }
}

// ---------------- tail: avg_attn (blocks 0..511) + gemm_o (512..1023) ----
// Both depend only on attn_fwd; one launch saves a dispatch gap and lets
// gemm_o blocks fill avg_attn's drain tail. LDS aliased via union (64KB ->
// 2 blocks/CU for both halves). bx%8 XCD mapping of each part preserved.
struct TailAvg { __bf16 Qs[2][128 * 64]; __bf16 Ks[2][128 * 64]; };  // 64KB
struct TailGo  { __bf16 As[2][64 * 64];  __bf16 Bs[2][128 * 64]; }; // 48KB
union TailSh { TailAvg a; TailGo g; };

__global__ __launch_bounds__(256, 2) void tail_fused(
    const __bf16* __restrict__ qb, const __bf16* __restrict__ kb,
    const float* __restrict__ linv_ws, float* __restrict__ avg_out,
    const __bf16* __restrict__ ob, const __bf16* __restrict__ wo,
    const float* __restrict__ bo, float* __restrict__ out) {
  __shared__ TailSh sh;
  const int bx = blockIdx.x;
  if (bx < 512) {
    avg_body(qb, kb, linv_ws, avg_out, bx,
             sh.a.Qs[0], sh.a.Qs[1], sh.a.Ks[0], sh.a.Ks[1]);
  } else {
    const int b2 = bx - 512;
    const int m = b2 & 63, n = b2 >> 6;
    gemm2<64>(ob, wo, bo, out, 3, 1.0f, m * 64, n * 128,
              sh.g.As[0], sh.g.As[1], sh.g.Bs[0], sh.g.Bs[1]);
  }
}

extern "C" void kernel_launch(void* const* d_in, const int* in_sizes, int n_in,
                              void* d_out, int out_size, void* d_ws, size_t ws_size,
                              hipStream_t stream) {
  (void)in_sizes; (void)n_in; (void)out_size; (void)ws_size;
  const float* query = (const float*)d_in[0];
  const float* key   = (const float*)d_in[1];
  const float* value = (const float*)d_in[2];
  const float* Wq = (const float*)d_in[3];
  const float* bq = (const float*)d_in[4];
  const float* Wk = (const float*)d_in[5];
  const float* bk = (const float*)d_in[6];
  const float* Wv = (const float*)d_in[7];
  const float* bv = (const float*)d_in[8];
  const float* Wo = (const float*)d_in[9];
  const float* bo = (const float*)d_in[10];

  char* ws = (char*)d_ws;
  size_t off = 0;
  auto wsalloc = [&](size_t bytes) -> void* {
    void* p = ws + off;
    off += (bytes + 255) & ~(size_t)255;
    return p;
  };
  const size_t XE = (size_t)MM * EE;
  const size_t WE = (size_t)EE * EE;
  __bf16* xq   = (__bf16*)wsalloc(XE * 2);
  __bf16* xk   = (__bf16*)wsalloc(XE * 2);
  __bf16* xv   = (__bf16*)wsalloc(XE * 2);
  __bf16* wqb  = (__bf16*)wsalloc(WE * 2);
  __bf16* wkb  = (__bf16*)wsalloc(WE * 2);
  __bf16* wvb  = (__bf16*)wsalloc(WE * 2);
  __bf16* wob  = (__bf16*)wsalloc(WE * 2);
  __bf16* qbuf = (__bf16*)wsalloc(XE * 2);
  __bf16* kbuf = (__bf16*)wsalloc(XE * 2);
  __bf16* vtbuf= (__bf16*)wsalloc(XE * 2);
  __bf16* obuf = (__bf16*)wsalloc(XE * 2);
  float* linv  = (float*)wsalloc((size_t)BBATCH * HN * TT * 4);

  CvtArgs ca;
  ca.src[0] = query; ca.dst[0] = xq;  ca.n4[0] = (int)(XE / 4);
  ca.src[1] = key;   ca.dst[1] = xk;  ca.n4[1] = (int)(XE / 4);
  ca.src[2] = value; ca.dst[2] = xv;  ca.n4[2] = (int)(XE / 4);
  ca.src[3] = Wq;    ca.dst[3] = wqb; ca.n4[3] = (int)(WE / 4);
  ca.src[4] = Wk;    ca.dst[4] = wkb; ca.n4[4] = (int)(WE / 4);
  ca.src[5] = Wv;    ca.dst[5] = wvb; ca.n4[5] = (int)(WE / 4);
  ca.src[6] = Wo;    ca.dst[6] = wob; ca.n4[6] = (int)(WE / 4);
  cvt_all<<<dim3(4096, 1, 7), 256, 0, stream>>>(ca);

  gemm_qkv8<<<dim3(192), 512, 0, stream>>>(xq, xk, xv, wqb, wkb, wvb,
                                           bq, bk, bv, qbuf, kbuf, vtbuf);

  attn_fwd<<<dim3(512), 256, 0, stream>>>(qbuf, kbuf, vtbuf, obuf, linv);

  float* avg_out = (float*)d_out + (size_t)TT * BBATCH * EE;
  tail_fused<<<dim3(1024), 256, 0, stream>>>(qbuf, kbuf, linv, avg_out,
                                             obuf, wob, bo, (float*)d_out);
}

// Round 2
// 240.546 us; speedup vs baseline: 1.0822x; 1.0822x over previous
//
#include <hip/hip_runtime.h>
#include <hip/hip_bf16.h>
#include <stdint.h>

#define HN 16      // heads
#define TT 2048    // seq len (T == S)
#define BBATCH 2
#define EE 1024
#define HD 64
#define MM 4096    // TT*BBATCH

// Q projection pre-scaled by 0.125*log2(e): exp2(q'.k) == exp(0.125*q.k).
#define SCALEQ 0.18033688011112042f

typedef __attribute__((ext_vector_type(8))) __bf16 bfrag;
typedef __attribute__((ext_vector_type(4))) float f32x4;
typedef __attribute__((ext_vector_type(4))) short s16x4;

__device__ __forceinline__ void gll16(const void* g, void* lds) {
  __builtin_amdgcn_global_load_lds(
      (const __attribute__((address_space(1))) void*)g,
      (__attribute__((address_space(3))) void*)lds, 16, 0, 0);
}

__device__ __forceinline__ f32x4 mfma_bf16(bfrag a, bfrag b, f32x4 c) {
  return __builtin_amdgcn_mfma_f32_16x16x32_bf16(a, b, c, 0, 0, 0);
}

// ---- XOR-swizzled 64-elem-row LDS tiles (16B chunk c of row r at c^(r&7)) --
__device__ __forceinline__ const bfrag* fragp(const __bf16* base, int row, int e) {
  return (const bfrag*)(base + row * 64 + ((((e >> 3) ^ row) & 7) << 3));
}
__device__ __forceinline__ void stage8(const __bf16* grow0, int gstride,
                                       __bf16* tile, int r0, int lane) {
  const int rr = lane >> 3;
  const int cl = (lane & 7) ^ rr;
  gll16(grow0 + (size_t)(r0 + rr) * gstride + cl * 8, tile + r0 * 64);
}

// counted-vmcnt barrier pair (T4 without full 8-phase):
//   barrier#1: all readers of the buffer we are about to overwrite are done.
//   (stage next tile here -- its loads stay in flight across both barriers)
//   vmcnt(N):  retire exactly the current tile's loads, keep next tile flying.
//   barrier#2: all waves' current-tile LDS writes have landed.
// sched_barrier(0) fences pin VMEM/DS ops to the correct side (rule #18).
__device__ __forceinline__ void barrier_fence() {
  __builtin_amdgcn_s_barrier();
  __builtin_amdgcn_sched_barrier(0);
}

// ---------------- fp32 -> bf16 conversion (7 tensors in one launch) -------
struct CvtArgs {
  const float* src[7];
  __bf16* dst[7];
  int n4[7];
};

__global__ __launch_bounds__(256) void cvt_all(CvtArgs a) {
  const int z = blockIdx.z;
  const int i = blockIdx.x * 256 + threadIdx.x;
  if (i < a.n4[z]) {
    float4 v = ((const float4*)a.src[z])[i];
    struct alignas(8) B4 { __bf16 a0, a1, a2, a3; };
    B4 o = {(__bf16)v.x, (__bf16)v.y, (__bf16)v.z, (__bf16)v.w};
    ((B4*)a.dst[z])[i] = o;
  }
}

// ---------------- GEMM core: BK=64, swizzled LDS, dbuf, counted vmcnt -----
template <int MT>
__device__ __forceinline__ void gemm2(const __bf16* __restrict__ X,
                                      const __bf16* __restrict__ W,
                                      const float* __restrict__ bias,
                                      void* __restrict__ out, int mode,
                                      float scale, int m0, int n0,
                                      __bf16* As0, __bf16* As1,
                                      __bf16* Bs0, __bf16* Bs1) {
  const int tid = threadIdx.x, lane = tid & 63, w = tid >> 6;
  const int wm = w >> 1, wn = w & 1;
  const int quad = lane >> 4, l16 = lane & 15;
  constexpr int FM = MT / 32;   // m-frags per wave
  constexpr int NLD = FM + 4;   // gll16 per thread per stage

  auto stageAB = [&](int buf, int k0) {
    __bf16* A = buf ? As1 : As0;
    __bf16* B = buf ? Bs1 : Bs0;
    #pragma unroll
    for (int c = 0; c < FM; ++c)
      stage8(X + (size_t)m0 * EE + k0, EE, A, w * (MT / 4) + c * 8, lane);
    #pragma unroll
    for (int c = 0; c < 4; ++c)
      stage8(W + (size_t)n0 * EE + k0, EE, B, w * 32 + c * 8, lane);
  };

  stageAB(0, 0);

  f32x4 acc[FM][4] = {};

  for (int it = 0; it < EE / 64; ++it) {
    const int cur = it & 1;
    barrier_fence();                       // readers of buf[1-cur] done
    if (it + 1 < EE / 64) {
      stageAB(1 - cur, (it + 1) * 64);     // next tile: stays in flight
      asm volatile("s_waitcnt vmcnt(%0)" :: "n"(NLD) : "memory");
    } else {
      asm volatile("s_waitcnt vmcnt(0)" ::: "memory");
    }
    barrier_fence();                       // all waves' cur-tile writes landed

    const __bf16* A = cur ? As1 : As0;
    const __bf16* B = cur ? Bs1 : Bs0;
    #pragma unroll
    for (int ks = 0; ks < 2; ++ks) {
      bfrag a[FM], b[4];
      #pragma unroll
      for (int f = 0; f < FM; ++f)
        a[f] = *fragp(A, wm * (MT / 2) + f * 16 + l16, ks * 32 + quad * 8);
      #pragma unroll
      for (int f = 0; f < 4; ++f)
        b[f] = *fragp(B, wn * 64 + f * 16 + l16, ks * 32 + quad * 8);
      #pragma unroll
      for (int fm = 0; fm < FM; ++fm)
        #pragma unroll
        for (int fn = 0; fn < 4; ++fn)
          acc[fm][fn] = mfma_bf16(a[fm], b[fn], acc[fm][fn]);
    }
  }

  float bv[4];
  #pragma unroll
  for (int fn = 0; fn < 4; ++fn) bv[fn] = bias[n0 + wn * 64 + fn * 16 + l16];

  #pragma unroll
  for (int fm = 0; fm < FM; ++fm) {
    #pragma unroll
    for (int r = 0; r < 4; ++r) {
      const int gm = m0 + wm * (MT / 2) + fm * 16 + quad * 4 + r;
      #pragma unroll
      for (int fn = 0; fn < 4; ++fn) {
        const int gn = n0 + wn * 64 + fn * 16 + l16;
        const float v = (acc[fm][fn][r] + bv[fn]) * scale;
        if (mode == 0) {
          const int t = gm >> 1, bb = gm & 1, h = gn >> 6, d = gn & 63;
          ((__bf16*)out)[(((size_t)(bb * HN + h)) * TT + t) * HD + d] = (__bf16)v;
        } else if (mode == 2) {
          const int s = gm >> 1, bb = gm & 1, h = gn >> 6, d = gn & 63;
          ((__bf16*)out)[(((size_t)(bb * HN + h)) * HD + d) * TT + s] = (__bf16)v;
        } else {
          ((float*)out)[(size_t)gm * EE + gn] = v;
        }
      }
    }
  }
}

// flat grid 768: bx = m + 32*(n + 8*z). bx%8 == m%8 -> the 8 n-blocks
// sharing one A-tile land on one XCD (A-tiles 1MB + B 2MB fit 4MB L2).
__global__ __launch_bounds__(256, 2) void gemm_qkv(
    const __bf16* __restrict__ xq, const __bf16* __restrict__ xk,
    const __bf16* __restrict__ xv, const __bf16* __restrict__ wq,
    const __bf16* __restrict__ wk, const __bf16* __restrict__ wv,
    const float* __restrict__ bq, const float* __restrict__ bk,
    const float* __restrict__ bv, __bf16* __restrict__ qo,
    __bf16* __restrict__ ko, __bf16* __restrict__ vo) {
  __shared__ __bf16 As[2][128 * 64];   // 32KB
  __shared__ __bf16 Bs[2][128 * 64];   // 32KB
  const int bx = blockIdx.x;
  const int m = bx & 31, n = (bx >> 5) & 7, z = bx >> 8;
  const __bf16 *X, *W;
  const float* bias;
  __bf16* out;
  int mode;
  float scale;
  if (z == 0)      { X = xq; W = wq; bias = bq; out = qo; mode = 0; scale = SCALEQ; }
  else if (z == 1) { X = xk; W = wk; bias = bk; out = ko; mode = 0; scale = 1.0f; }
  else             { X = xv; W = wv; bias = bv; out = vo; mode = 2; scale = 1.0f; }
  gemm2<128>(X, W, bias, out, mode, scale, m * 128, n * 128,
             As[0], As[1], Bs[0], Bs[1]);
}

// ---------------- flash attention fwd: O (normalized) + linv -------------
__global__ __launch_bounds__(256, 2) void attn_fwd(const __bf16* __restrict__ qb,
                                                   const __bf16* __restrict__ kb,
                                                   const __bf16* __restrict__ vtb,
                                                   __bf16* __restrict__ ob,
                                                   float* __restrict__ linv_ws) {
  union Sh {
    __bf16 kv[2][2][2][64 * 64];  // [pair][K=0/V=1][buf] 64KB
    float om[2][64 * 64];         // epilogue O-merge scratch (32KB, aliased)
  };
  __shared__ Sh sm;
  __shared__ float Lsum[2][128];
  __shared__ float LinvS[128];

  const int tid = threadIdx.x, lane = tid & 63, w = tid >> 6;
  const int p = w >> 1, tw = w & 1;
  const int quad = lane >> 4, l16 = lane & 15;

  const int bx = blockIdx.x;
  const int xcd = bx & 7, slot = bx >> 3;
  const int bhi = xcd * 4 + (slot >> 4);
  const int t0 = (slot & 15) * 128;
  const int b = bhi >> 4, h = bhi & 15;
  const size_t bh = (size_t)(b * HN + h);

  const __bf16* qbase = qb + (bh * TT + t0) * HD;
  const __bf16* kbase = kb + bh * TT * HD;
  const __bf16* vbase = vtb + bh * HD * TT;
  const int sBase = p * 1024;

  #pragma unroll
  for (int c = 0; c < 4; ++c) {
    stage8(kbase + (size_t)sBase * HD, HD, sm.kv[p][0][0], tw * 32 + c * 8, lane);
    stage8(vbase + sBase, TT, sm.kv[p][1][0], tw * 32 + c * 8, lane);
  }

  bfrag qf[4][2];
  #pragma unroll
  for (int fn = 0; fn < 4; ++fn)
    #pragma unroll
    for (int ks = 0; ks < 2; ++ks)
      qf[fn][ks] = *(const bfrag*)(qbase +
          (size_t)(tw * 64 + fn * 16 + l16) * HD + ks * 32 + quad * 8);

  bfrag ones;
  {
    union { short s[8]; bfrag v; } u;
    #pragma unroll
    for (int i = 0; i < 8; ++i) u.s[i] = 0x3F80;   // bf16 1.0
    ones = u.v;
  }

  f32x4 oacc[4][4] = {};   // [fm_d][fn_t] of O^T
  f32x4 lacc[4] = {};      // row sums via ones-MFMA (all r identical)

  for (int it = 0; it < 16; ++it) {
    const int cur = it & 1;
    barrier_fence();                     // readers of buf[1-cur] done
    if (it + 1 < 16) {
      const int s1 = sBase + (it + 1) * 64;
      #pragma unroll
      for (int c = 0; c < 4; ++c) {
        stage8(kbase + (size_t)s1 * HD, HD, sm.kv[p][0][1 - cur], tw * 32 + c * 8, lane);
        stage8(vbase + s1, TT, sm.kv[p][1][1 - cur], tw * 32 + c * 8, lane);
      }
      asm volatile("s_waitcnt vmcnt(8)" ::: "memory");
    } else {
      asm volatile("s_waitcnt vmcnt(0)" ::: "memory");
    }
    barrier_fence();                     // cur-tile K/V writes landed

    // ---- S^T[s][t] = K.Q (scale+log2e folded into Q)
    f32x4 sacc[4][4] = {};
    #pragma unroll
    for (int ks = 0; ks < 2; ++ks) {
      bfrag kf[4];
      #pragma unroll
      for (int fm = 0; fm < 4; ++fm)
        kf[fm] = *fragp(sm.kv[p][0][cur], fm * 16 + l16, ks * 32 + quad * 8);
      #pragma unroll
      for (int fm = 0; fm < 4; ++fm)
        #pragma unroll
        for (int fn = 0; fn < 4; ++fn)
          sacc[fm][fn] = mfma_bf16(kf[fm], qf[fn][ks], sacc[fm][fn]);
    }

    // ---- exp2 in registers; pack 16-s frag pairs into x32 B-operands
    union PB { __bf16 hh[8]; bfrag v; } pb[2][4];
    #pragma unroll
    for (int fm = 0; fm < 4; ++fm)
      #pragma unroll
      for (int fn = 0; fn < 4; ++fn) {
        const float p0 = __builtin_amdgcn_exp2f(sacc[fm][fn][0]);
        const float p1 = __builtin_amdgcn_exp2f(sacc[fm][fn][1]);
        const float p2 = __builtin_amdgcn_exp2f(sacc[fm][fn][2]);
        const float p3 = __builtin_amdgcn_exp2f(sacc[fm][fn][3]);
        const int hb = (fm & 1) * 4;
        pb[fm >> 1][fn].hh[hb + 0] = (__bf16)p0;
        pb[fm >> 1][fn].hh[hb + 1] = (__bf16)p1;
        pb[fm >> 1][fn].hh[hb + 2] = (__bf16)p2;
        pb[fm >> 1][fn].hh[hb + 3] = (__bf16)p3;
      }

    // ---- O^T[d][t] += V^T.P^T ; row sums l[t] += 1.P^T on the MFMA pipe
    #pragma unroll
    for (int ks = 0; ks < 2; ++ks) {
      bfrag vf[4];
      #pragma unroll
      for (int fm = 0; fm < 4; ++fm) {
        const __bf16* base = sm.kv[p][1][cur] + (fm * 16 + l16) * 64;
        const int sw = l16 & 7, qh = quad >> 1, qo = (quad & 1) * 4;
        union VF { s16x4 q[2]; bfrag v; } u;
        u.q[0] = *(const s16x4*)(base + (((ks * 4 + qh) ^ sw) << 3) + qo);
        u.q[1] = *(const s16x4*)(base + (((ks * 4 + 2 + qh) ^ sw) << 3) + qo);
        vf[fm] = u.v;
      }
      #pragma unroll
      for (int fn = 0; fn < 4; ++fn)
        lacc[fn] = mfma_bf16(ones, pb[ks][fn].v, lacc[fn]);
      #pragma unroll
      for (int fm = 0; fm < 4; ++fm)
        #pragma unroll
        for (int fn = 0; fn < 4; ++fn)
          oacc[fm][fn] = mfma_bf16(vf[fm], pb[ks][fn].v, oacc[fm][fn]);
    }
  }

  // ---- lacc[fn][r] holds l for t = fn*16+l16 (identical across r, quads)
  if (quad == 0)
    #pragma unroll
    for (int fn = 0; fn < 4; ++fn)
      Lsum[p][tw * 64 + fn * 16 + l16] = lacc[fn][0];

  __syncthreads();   // Lsum visible; all K/V reads done -> om may alias

  if (p == 1) {
    #pragma unroll
    for (int fm = 0; fm < 4; ++fm)
      #pragma unroll
      for (int fn = 0; fn < 4; ++fn)
        #pragma unroll
        for (int r = 0; r < 4; ++r)
          sm.om[tw][(fm * 16 + quad * 4 + r) * 64 + fn * 16 + l16] = oacc[fm][fn][r];
  }
  if (tid < 128) {
    const float linv = 1.0f / (Lsum[0][tid] + Lsum[1][tid]);
    LinvS[tid] = linv;
    linv_ws[bh * TT + t0 + tid] = linv;
  }
  __syncthreads();

  if (p == 0) {
    float li[4];
    #pragma unroll
    for (int fn = 0; fn < 4; ++fn) li[fn] = LinvS[tw * 64 + fn * 16 + l16];
    #pragma unroll
    for (int fm = 0; fm < 4; ++fm)
      #pragma unroll
      for (int fn = 0; fn < 4; ++fn) {
        const int t = t0 + tw * 64 + fn * 16 + l16;
        struct alignas(8) B4 { __bf16 a0, a1, a2, a3; };
        B4 o;
        __bf16* op = &o.a0;
        #pragma unroll
        for (int r = 0; r < 4; ++r) {
          const float v = (oacc[fm][fn][r] +
              sm.om[tw][(fm * 16 + quad * 4 + r) * 64 + fn * 16 + l16]) * li[fn];
          op[r] = (__bf16)v;
        }
        *(B4*)(ob + ((size_t)t * BBATCH + b) * EE + h * HD + fm * 16 + quad * 4) = o;
      }
  }
}

// ---------------- avg_w body: mean over heads of softmax probs ----------
__device__ __forceinline__ void avg_body(const __bf16* __restrict__ qb,
                                         const __bf16* __restrict__ kb,
                                         const float* __restrict__ linv_ws,
                                         float* __restrict__ avg_out, int bx,
                                         __bf16* Qs0, __bf16* Qs1,
                                         __bf16* Ks0, __bf16* Ks1) {
  const int tid = threadIdx.x, lane = tid & 63, w = tid >> 6;
  const int wm = w >> 1, wn = w & 1;
  const int quad = lane >> 4, l16 = lane & 15;

  const int xcd = bx & 7, slot = bx >> 3;
  const int bti = xcd * 4 + (slot >> 4);
  const int s0 = (slot & 15) * 128;
  const int b = bti >> 4, t0 = (bti & 15) * 128;

  const __bf16* qt = qb + (((size_t)b * HN) * TT + t0) * HD;
  const __bf16* kt = kb + (((size_t)b * HN) * TT + s0) * HD;
  const float* lrow0 = linv_ws + ((size_t)b * HN) * TT + t0 + wm * 64;

  #pragma unroll
  for (int c = 0; c < 4; ++c) {
    stage8(qt, HD, Qs0, w * 32 + c * 8, lane);
    stage8(kt, HD, Ks0, w * 32 + c * 8, lane);
  }

  f32x4 aacc[4][4] = {};

  for (int h = 0; h < HN; ++h) {
    const int cur = h & 1;
    barrier_fence();                     // readers of buf[1-cur] done
    if (h + 1 < HN) {
      const __bf16* qn = qt + (size_t)(h + 1) * TT * HD;
      const __bf16* kn = kt + (size_t)(h + 1) * TT * HD;
      __bf16* Qn = cur ? Qs0 : Qs1;
      __bf16* Kn = cur ? Ks0 : Ks1;
      #pragma unroll
      for (int c = 0; c < 4; ++c) {
        stage8(qn, HD, Qn, w * 32 + c * 8, lane);
        stage8(kn, HD, Kn, w * 32 + c * 8, lane);
      }
      asm volatile("s_waitcnt vmcnt(8)" ::: "memory");
    } else {
      asm volatile("s_waitcnt vmcnt(0)" ::: "memory");
    }
    barrier_fence();                     // cur-head Q/K writes landed

    const __bf16* Qc = cur ? Qs1 : Qs0;
    const __bf16* Kc = cur ? Ks1 : Ks0;
    f32x4 sacc[4][4] = {};
    #pragma unroll
    for (int ks = 0; ks < 2; ++ks) {
      bfrag qf4[4], kf4[4];
      #pragma unroll
      for (int f = 0; f < 4; ++f)
        qf4[f] = *fragp(Qc, wm * 64 + f * 16 + l16, ks * 32 + quad * 8);
      #pragma unroll
      for (int f = 0; f < 4; ++f)
        kf4[f] = *fragp(Kc, wn * 64 + f * 16 + l16, ks * 32 + quad * 8);
      #pragma unroll
      for (int fm = 0; fm < 4; ++fm)
        #pragma unroll
        for (int fn = 0; fn < 4; ++fn)
          sacc[fm][fn] = mfma_bf16(qf4[fm], kf4[fn], sacc[fm][fn]);
    }

    const float* lr = lrow0 + (size_t)h * TT;
    f32x4 lvv[4];
    #pragma unroll
    for (int fm = 0; fm < 4; ++fm)
      lvv[fm] = *(const f32x4*)(lr + fm * 16 + quad * 4);

    #pragma unroll
    for (int fm = 0; fm < 4; ++fm)
      #pragma unroll
      for (int fn = 0; fn < 4; ++fn)
        #pragma unroll
        for (int r = 0; r < 4; ++r)
          aacc[fm][fn][r] += __builtin_amdgcn_exp2f(sacc[fm][fn][r]) * lvv[fm][r];
  }

  const float invh = 1.0f / (float)HN;
  #pragma unroll
  for (int fm = 0; fm < 4; ++fm)
    #pragma unroll
    for (int r = 0; r < 4; ++r) {
      const int t = t0 + wm * 64 + fm * 16 + quad * 4 + r;
      #pragma unroll
      for (int fn = 0; fn < 4; ++fn) {
        const int s = s0 + wn * 64 + fn * 16 + l16;
        avg_out[((size_t)b * TT + t) * TT + s] = aacc[fm][fn][r] * invh;
      }
    }
}

// ---------------- tail: avg_attn (blocks 0..511) + gemm_o (512..1023) ----
struct TailAvg { __bf16 Qs[2][128 * 64]; __bf16 Ks[2][128 * 64]; };  // 64KB
struct TailGo  { __bf16 As[2][64 * 64];  __bf16 Bs[2][128 * 64]; }; // 48KB
union TailSh { TailAvg a; TailGo g; };

__global__ __launch_bounds__(256, 2) void tail_fused(
    const __bf16* __restrict__ qb, const __bf16* __restrict__ kb,
    const float* __restrict__ linv_ws, float* __restrict__ avg_out,
    const __bf16* __restrict__ ob, const __bf16* __restrict__ wo,
    const float* __restrict__ bo, float* __restrict__ out) {
  __shared__ TailSh sh;
  const int bx = blockIdx.x;
  if (bx < 512) {
    avg_body(qb, kb, linv_ws, avg_out, bx,
             sh.a.Qs[0], sh.a.Qs[1], sh.a.Ks[0], sh.a.Ks[1]);
  } else {
    const int b2 = bx - 512;
    const int m = b2 & 63, n = b2 >> 6;
    gemm2<64>(ob, wo, bo, out, 3, 1.0f, m * 64, n * 128,
              sh.g.As[0], sh.g.As[1], sh.g.Bs[0], sh.g.Bs[1]);
  }
}

extern "C" void kernel_launch(void* const* d_in, const int* in_sizes, int n_in,
                              void* d_out, int out_size, void* d_ws, size_t ws_size,
                              hipStream_t stream) {
  (void)in_sizes; (void)n_in; (void)out_size; (void)ws_size;
  const float* query = (const float*)d_in[0];
  const float* key   = (const float*)d_in[1];
  const float* value = (const float*)d_in[2];
  const float* Wq = (const float*)d_in[3];
  const float* bq = (const float*)d_in[4];
  const float* Wk = (const float*)d_in[5];
  const float* bk = (const float*)d_in[6];
  const float* Wv = (const float*)d_in[7];
  const float* bv = (const float*)d_in[8];
  const float* Wo = (const float*)d_in[9];
  const float* bo = (const float*)d_in[10];

  char* ws = (char*)d_ws;
  size_t off = 0;
  auto wsalloc = [&](size_t bytes) -> void* {
    void* p = ws + off;
    off += (bytes + 255) & ~(size_t)255;
    return p;
  };
  const size_t XE = (size_t)MM * EE;
  const size_t WE = (size_t)EE * EE;
  __bf16* xq   = (__bf16*)wsalloc(XE * 2);
  __bf16* xk   = (__bf16*)wsalloc(XE * 2);
  __bf16* xv   = (__bf16*)wsalloc(XE * 2);
  __bf16* wqb  = (__bf16*)wsalloc(WE * 2);
  __bf16* wkb  = (__bf16*)wsalloc(WE * 2);
  __bf16* wvb  = (__bf16*)wsalloc(WE * 2);
  __bf16* wob  = (__bf16*)wsalloc(WE * 2);
  __bf16* qbuf = (__bf16*)wsalloc(XE * 2);
  __bf16* kbuf = (__bf16*)wsalloc(XE * 2);
  __bf16* vtbuf= (__bf16*)wsalloc(XE * 2);
  __bf16* obuf = (__bf16*)wsalloc(XE * 2);
  float* linv  = (float*)wsalloc((size_t)BBATCH * HN * TT * 4);

  CvtArgs ca;
  ca.src[0] = query; ca.dst[0] = xq;  ca.n4[0] = (int)(XE / 4);
  ca.src[1] = key;   ca.dst[1] = xk;  ca.n4[1] = (int)(XE / 4);
  ca.src[2] = value; ca.dst[2] = xv;  ca.n4[2] = (int)(XE / 4);
  ca.src[3] = Wq;    ca.dst[3] = wqb; ca.n4[3] = (int)(WE / 4);
  ca.src[4] = Wk;    ca.dst[4] = wkb; ca.n4[4] = (int)(WE / 4);
  ca.src[5] = Wv;    ca.dst[5] = wvb; ca.n4[5] = (int)(WE / 4);
  ca.src[6] = Wo;    ca.dst[6] = wob; ca.n4[6] = (int)(WE / 4);
  cvt_all<<<dim3(4096, 1, 7), 256, 0, stream>>>(ca);

  gemm_qkv<<<dim3(768), 256, 0, stream>>>(xq, xk, xv, wqb, wkb, wvb,
                                          bq, bk, bv, qbuf, kbuf, vtbuf);

  attn_fwd<<<dim3(512), 256, 0, stream>>>(qbuf, kbuf, vtbuf, obuf, linv);

  float* avg_out = (float*)d_out + (size_t)TT * BBATCH * EE;
  tail_fused<<<dim3(1024), 256, 0, stream>>>(qbuf, kbuf, linv, avg_out,
                                             obuf, wob, bo, (float*)d_out);
}